// Round 3
// baseline (24.988 us; speedup 1.0000x reference)
//
#include <hip/hip_runtime.h>
#include <cfloat>

#define TPB 64          // TOKENS_PER_BLOCK
#define SCPB 4          // SUB_CHUNK_PER_BLOCK
#define TPSC 16         // TOKENS_PER_SUB_CHUNK

typedef float vfloat4 __attribute__((ext_vector_type(4)));

__global__ __launch_bounds__(256) void paged_minmax_kernel(
    const float* __restrict__ keys,
    const int* __restrict__ block_tables,
    const int* __restrict__ cu_seqlens,
    const int* __restrict__ heads_idx,
    float* __restrict__ out,
    int B, int MB, int H, int D, int Hp)
{
    const int n_chunks = MB * SCPB;
    const int bc = blockIdx.x;
    const int b = bc / n_chunks;
    const int c = bc - b * n_chunks;

    const int len = cu_seqlens[b + 1] - cu_seqlens[b];
    int nv = len - c * TPSC;
    if (nv > TPSC) nv = TPSC;

    const int tid = threadIdx.x;             // 0..Hp*D/4-1
    const int d4_per_head = D >> 2;          // 32 for D=128
    const int h = tid / d4_per_head;
    const int d4 = tid - h * d4_per_head;

    const size_t s_stride = (size_t)B * n_chunks * Hp * D;   // min->max offset
    float* out_min = out + ((size_t)b * n_chunks + c) * (size_t)(Hp * D) + (size_t)tid * 4;
    float* out_max = out_min + s_stride;

    if (nv <= 0) {
        vfloat4 z = (vfloat4)0.f;
        __builtin_nontemporal_store(z, reinterpret_cast<vfloat4*>(out_min));
        __builtin_nontemporal_store(z, reinterpret_cast<vfloat4*>(out_max));
        return;
    }

    const int blk = block_tables[b * MB + (c >> 2)];
    const int t0 = (c & (SCPB - 1)) * TPSC;
    const int hp = heads_idx[h];

    const vfloat4* src = reinterpret_cast<const vfloat4*>(
        keys + ((size_t)blk * TPB + t0) * (size_t)(H * D) + (size_t)hp * D) + d4;
    const int tstride = (H * D) >> 2;        // vfloat4 units between tokens

    vfloat4 x0 = __builtin_nontemporal_load(src);
    vfloat4 mn0 = x0, mx0 = x0;

    if (nv == TPSC) {
        // common case: all 16 loads independent; two accumulator chains
        vfloat4 x1 = __builtin_nontemporal_load(src + tstride);
        vfloat4 mn1 = x1, mx1 = x1;
        #pragma unroll
        for (int t = 2; t < TPSC; t += 2) {
            vfloat4 a = __builtin_nontemporal_load(src + (size_t)t * tstride);
            vfloat4 bq = __builtin_nontemporal_load(src + (size_t)(t + 1) * tstride);
            mn0 = __builtin_elementwise_min(mn0, a);
            mx0 = __builtin_elementwise_max(mx0, a);
            mn1 = __builtin_elementwise_min(mn1, bq);
            mx1 = __builtin_elementwise_max(mx1, bq);
        }
        mn0 = __builtin_elementwise_min(mn0, mn1);
        mx0 = __builtin_elementwise_max(mx0, mx1);
    } else {
        for (int t = 1; t < nv; ++t) {
            vfloat4 a = __builtin_nontemporal_load(src + (size_t)t * tstride);
            mn0 = __builtin_elementwise_min(mn0, a);
            mx0 = __builtin_elementwise_max(mx0, a);
        }
    }

    __builtin_nontemporal_store(mn0, reinterpret_cast<vfloat4*>(out_min));
    __builtin_nontemporal_store(mx0, reinterpret_cast<vfloat4*>(out_max));
}

extern "C" void kernel_launch(void* const* d_in, const int* in_sizes, int n_in,
                              void* d_out, int out_size, void* d_ws, size_t ws_size,
                              hipStream_t stream) {
    const float* keys        = (const float*)d_in[0];
    const int*   block_tables= (const int*)d_in[1];
    const int*   cu_seqlens  = (const int*)d_in[2];
    const int*   heads_idx   = (const int*)d_in[3];
    float* out = (float*)d_out;

    const int B  = in_sizes[2] - 1;                 // 4
    const int MB = in_sizes[1] / B;                 // 128
    const int Hp = in_sizes[3];                     // 8
    const int D  = 128;
    const long long num_blocks_tokens = (long long)in_sizes[1] * TPB; // B*MB*64
    const int H  = (int)((long long)in_sizes[0] / num_blocks_tokens / D); // 8

    const int n_chunks = MB * SCPB;
    const int grid = B * n_chunks;                  // 2048
    const int threads = (Hp * D) / 4;               // 256

    paged_minmax_kernel<<<grid, threads, 0, stream>>>(
        keys, block_tables, cu_seqlens, heads_idx, out, B, MB, H, D, Hp);
}

// Round 4
// 24.425 us; speedup vs baseline: 1.0231x; 1.0231x over previous
//
#include <hip/hip_runtime.h>
#include <cfloat>

#define TPB 64          // TOKENS_PER_BLOCK
#define SCPB 4          // SUB_CHUNK_PER_BLOCK
#define TPSC 16         // TOKENS_PER_SUB_CHUNK

typedef float vfloat4 __attribute__((ext_vector_type(4)));

__global__ __launch_bounds__(256) void paged_minmax_kernel(
    const float* __restrict__ keys,
    const int* __restrict__ block_tables,
    const int* __restrict__ cu_seqlens,
    const int* __restrict__ heads_idx,
    float* __restrict__ out,
    int B, int MB, int H, int D, int Hp)
{
    const int n_chunks = MB * SCPB;
    const int bc = blockIdx.x;
    const int b = bc / n_chunks;
    const int c = bc - b * n_chunks;

    const int tid = threadIdx.x;             // 0..Hp*D/4-1
    const int d4_per_head = D >> 2;          // 32 for D=128
    const int h = tid / d4_per_head;
    const int d4 = tid - h * d4_per_head;

    // Issue the gather-dependent loads as early as possible — every main
    // load's address depends on hp and blk.
    const int hp  = heads_idx[h];
    const int blk = block_tables[b * MB + (c >> 2)];
    const int len = cu_seqlens[b + 1] - cu_seqlens[b];

    int nv = len - c * TPSC;
    if (nv > TPSC) nv = TPSC;

    const size_t s_stride = (size_t)B * n_chunks * Hp * D;   // min->max offset
    float* out_min = out + ((size_t)b * n_chunks + c) * (size_t)(Hp * D) + (size_t)tid * 4;
    float* out_max = out_min + s_stride;

    if (nv <= 0) {
        vfloat4 z = (vfloat4)0.f;
        __builtin_nontemporal_store(z, reinterpret_cast<vfloat4*>(out_min));
        __builtin_nontemporal_store(z, reinterpret_cast<vfloat4*>(out_max));
        return;
    }

    const int t0 = (c & (SCPB - 1)) * TPSC;

    const vfloat4* src = reinterpret_cast<const vfloat4*>(
        keys + ((size_t)blk * TPB + t0) * (size_t)(H * D) + (size_t)hp * D) + d4;
    const int tstride = (H * D) >> 2;        // vfloat4 units between tokens

    vfloat4 x0 = src[0];
    vfloat4 mn0 = x0, mx0 = x0;

    if (nv == TPSC) {
        // common case: all 16 loads independent; two accumulator chains
        vfloat4 x1 = src[tstride];
        vfloat4 mn1 = x1, mx1 = x1;
        #pragma unroll
        for (int t = 2; t < TPSC; t += 2) {
            vfloat4 a  = src[(size_t)t * tstride];
            vfloat4 bq = src[(size_t)(t + 1) * tstride];
            mn0 = __builtin_elementwise_min(mn0, a);
            mx0 = __builtin_elementwise_max(mx0, a);
            mn1 = __builtin_elementwise_min(mn1, bq);
            mx1 = __builtin_elementwise_max(mx1, bq);
        }
        mn0 = __builtin_elementwise_min(mn0, mn1);
        mx0 = __builtin_elementwise_max(mx0, mx1);
    } else {
        for (int t = 1; t < nv; ++t) {
            vfloat4 a = src[(size_t)t * tstride];
            mn0 = __builtin_elementwise_min(mn0, a);
            mx0 = __builtin_elementwise_max(mx0, a);
        }
    }

    __builtin_nontemporal_store(mn0, reinterpret_cast<vfloat4*>(out_min));
    __builtin_nontemporal_store(mx0, reinterpret_cast<vfloat4*>(out_max));
}

extern "C" void kernel_launch(void* const* d_in, const int* in_sizes, int n_in,
                              void* d_out, int out_size, void* d_ws, size_t ws_size,
                              hipStream_t stream) {
    const float* keys        = (const float*)d_in[0];
    const int*   block_tables= (const int*)d_in[1];
    const int*   cu_seqlens  = (const int*)d_in[2];
    const int*   heads_idx   = (const int*)d_in[3];
    float* out = (float*)d_out;

    const int B  = in_sizes[2] - 1;                 // 4
    const int MB = in_sizes[1] / B;                 // 128
    const int Hp = in_sizes[3];                     // 8
    const int D  = 128;
    const long long num_blocks_tokens = (long long)in_sizes[1] * TPB; // B*MB*64
    const int H  = (int)((long long)in_sizes[0] / num_blocks_tokens / D); // 8

    const int n_chunks = MB * SCPB;
    const int grid = B * n_chunks;                  // 2048
    const int threads = (Hp * D) / 4;               // 256

    paged_minmax_kernel<<<grid, threads, 0, stream>>>(
        keys, block_tables, cu_seqlens, heads_idx, out, B, MB, H, D, Hp);
}

// Round 5
// 23.451 us; speedup vs baseline: 1.0655x; 1.0415x over previous
//
#include <hip/hip_runtime.h>
#include <cfloat>

#define TPB 64          // TOKENS_PER_BLOCK
#define SCPB 4          // SUB_CHUNK_PER_BLOCK
#define TPSC 16         // TOKENS_PER_SUB_CHUNK

typedef float vfloat4 __attribute__((ext_vector_type(4)));

// One workgroup per page (64 tokens = 4 sub-chunks). 1024 threads:
// thread = (sub_chunk(2b) , h(3b) , d4(5b)). Per-thread work identical to the
// 256-thread version (16 loads, 2 stores) — only the grid is 4x smaller.
__global__ __launch_bounds__(1024) void paged_minmax_kernel(
    const float* __restrict__ keys,
    const int* __restrict__ block_tables,
    const int* __restrict__ cu_seqlens,
    const int* __restrict__ heads_idx,
    float* __restrict__ out,
    int B, int MB, int H, int D, int Hp)
{
    const int n_chunks = MB * SCPB;
    const int page = blockIdx.x;             // 0 .. B*MB-1
    const int b = page / MB;
    const int p = page - b * MB;

    const int tid = threadIdx.x;             // 0..1023
    const int ci = tid >> 8;                 // sub-chunk within page, 0..3
    const int t256 = tid & 255;
    const int d4_per_head = D >> 2;          // 32 for D=128
    const int h = t256 / d4_per_head;
    const int d4 = t256 - h * d4_per_head;

    const int c = p * SCPB + ci;             // global chunk within batch row

    // Early index loads — every main load's address depends on hp and blk.
    const int hp  = heads_idx[h];
    const int blk = block_tables[b * MB + p];
    const int len = cu_seqlens[b + 1] - cu_seqlens[b];

    int nv = len - c * TPSC;
    if (nv > TPSC) nv = TPSC;

    const size_t s_stride = (size_t)B * n_chunks * Hp * D;   // min->max offset
    float* out_min = out + ((size_t)b * n_chunks + c) * (size_t)(Hp * D) + (size_t)t256 * 4;
    float* out_max = out_min + s_stride;

    if (nv <= 0) {
        vfloat4 z = (vfloat4)0.f;
        __builtin_nontemporal_store(z, reinterpret_cast<vfloat4*>(out_min));
        __builtin_nontemporal_store(z, reinterpret_cast<vfloat4*>(out_max));
        return;
    }

    const int t0 = ci * TPSC;

    const vfloat4* src = reinterpret_cast<const vfloat4*>(
        keys + ((size_t)blk * TPB + t0) * (size_t)(H * D) + (size_t)hp * D) + d4;
    const int tstride = (H * D) >> 2;        // vfloat4 units between tokens

    vfloat4 x0 = src[0];
    vfloat4 mn0 = x0, mx0 = x0;

    if (nv == TPSC) {
        // common case: all 16 loads independent; two accumulator chains
        vfloat4 x1 = src[tstride];
        vfloat4 mn1 = x1, mx1 = x1;
        #pragma unroll
        for (int t = 2; t < TPSC; t += 2) {
            vfloat4 a  = src[(size_t)t * tstride];
            vfloat4 bq = src[(size_t)(t + 1) * tstride];
            mn0 = __builtin_elementwise_min(mn0, a);
            mx0 = __builtin_elementwise_max(mx0, a);
            mn1 = __builtin_elementwise_min(mn1, bq);
            mx1 = __builtin_elementwise_max(mx1, bq);
        }
        mn0 = __builtin_elementwise_min(mn0, mn1);
        mx0 = __builtin_elementwise_max(mx0, mx1);
    } else {
        for (int t = 1; t < nv; ++t) {
            vfloat4 a = src[(size_t)t * tstride];
            mn0 = __builtin_elementwise_min(mn0, a);
            mx0 = __builtin_elementwise_max(mx0, a);
        }
    }

    __builtin_nontemporal_store(mn0, reinterpret_cast<vfloat4*>(out_min));
    __builtin_nontemporal_store(mx0, reinterpret_cast<vfloat4*>(out_max));
}

extern "C" void kernel_launch(void* const* d_in, const int* in_sizes, int n_in,
                              void* d_out, int out_size, void* d_ws, size_t ws_size,
                              hipStream_t stream) {
    const float* keys        = (const float*)d_in[0];
    const int*   block_tables= (const int*)d_in[1];
    const int*   cu_seqlens  = (const int*)d_in[2];
    const int*   heads_idx   = (const int*)d_in[3];
    float* out = (float*)d_out;

    const int B  = in_sizes[2] - 1;                 // 4
    const int MB = in_sizes[1] / B;                 // 128
    const int Hp = in_sizes[3];                     // 8
    const int D  = 128;
    const long long num_blocks_tokens = (long long)in_sizes[1] * TPB; // B*MB*64
    const int H  = (int)((long long)in_sizes[0] / num_blocks_tokens / D); // 8

    const int grid = B * MB;                        // 512 pages
    const int threads = SCPB * (Hp * D) / 4;        // 1024

    paged_minmax_kernel<<<grid, threads, 0, stream>>>(
        keys, block_tables, cu_seqlens, heads_idx, out, B, MB, H, D, Hp);
}